// Round 6
// baseline (96.268 us; speedup 1.0000x reference)
//
#include <hip/hip_runtime.h>

#define CC 512
#define TT 4096
#define NB 4
#define NH 8
#define HD 64

typedef __attribute__((ext_vector_type(8))) short s16x8;
typedef __attribute__((ext_vector_type(4))) float f32x4;
typedef __attribute__((ext_vector_type(4))) unsigned int u32x4;
typedef __attribute__((ext_vector_type(2))) unsigned int u32x2;

// float -> bf16 bits, round-to-nearest-even
__device__ __forceinline__ short f2bf(float f) {
    unsigned u = __float_as_uint(f);
    unsigned r = (u + 0x7fffu + ((u >> 16) & 1u)) >> 16;
    return (short)r;
}
__device__ __forceinline__ unsigned pkbf(float a, float b) {
    return (unsigned)(unsigned short)f2bf(a) | ((unsigned)(unsigned short)f2bf(b) << 16);
}

__device__ __forceinline__ void gld_lds16(const void* g, void* s) {
    __builtin_amdgcn_global_load_lds(
        (const __attribute__((address_space(1))) unsigned int*)g,
        (__attribute__((address_space(3))) unsigned int*)s, 16, 0, 0);
}

// ---------------- weight fp32 -> bf16 (4 matrices concatenated) ----------------
__global__ __launch_bounds__(256) void cvt_w_k(const float* __restrict__ w0,
                                               const float* __restrict__ w1,
                                               const float* __restrict__ w2,
                                               const float* __restrict__ w3,
                                               short* __restrict__ dst) {
    int i = blockIdx.x * 256 + threadIdx.x;  // 4*262144 total
    const float* s = (i < 262144) ? w0 : (i < 524288) ? w1 : (i < 786432) ? w2 : w3;
    dst[i] = f2bf(s[i & 262143]);
}

// ---------- transpose+convert: fp32 (B,C,T) -> bf16 (B,T,C), x and cond -------
__global__ __launch_bounds__(256) void trans_k(const float* __restrict__ x,
                                               const float* __restrict__ cond,
                                               short* __restrict__ xT,
                                               short* __restrict__ condT) {
    __shared__ float tile[64][65];
    int z = blockIdx.z;          // 0..7
    int b = z & 3;
    const float* src = (z < 4 ? x : cond) + (size_t)b * CC * TT;
    short* dst = (z < 4 ? xT : condT) + (size_t)b * TT * CC;
    int tx = threadIdx.x & 63, ty = threadIdx.x >> 6;
    int t0 = blockIdx.x * 64, c0 = blockIdx.y * 64;
#pragma unroll
    for (int r = 0; r < 64; r += 4)
        tile[ty + r][tx] = src[(size_t)(c0 + ty + r) * TT + t0 + tx];
    __syncthreads();
#pragma unroll
    for (int r = 0; r < 64; r += 4)
        dst[(size_t)(t0 + ty + r) * CC + c0 + tx] = f2bf(tile[tx][ty + r]);
}

// ---------------- 128x128x64 bf16 MFMA GEMM core ----------------
// Wm: [512][512] bf16 (o,k) row-major. Sm: [4096][512] bf16 (t,k) row-major.
// OMODE=0: Df[o][t] fp32. OMODE=1: Db[t][o] bf16 (swapped operands).
// OMODE=2: Db[o][t] bf16.
template <int OMODE>
__device__ __forceinline__ void gemm128(const short* __restrict__ Wm,
                                        const short* __restrict__ Sm,
                                        const float* __restrict__ bias,
                                        float* __restrict__ Df,
                                        short* __restrict__ Db) {
    __shared__ short Al[128 * 64] __attribute__((aligned(16)));
    __shared__ short Bl[128 * 64] __attribute__((aligned(16)));
    const int tid = threadIdx.x;
    const int lane = tid & 63;
    const int wid = tid >> 6;
    const int o0 = blockIdx.y * 128;
    const int t0 = blockIdx.x * 128;
    const int wm = (wid >> 1) * 64;
    const int wn = (wid & 1) * 64;

    f32x4 acc[4][4];
#pragma unroll
    for (int i = 0; i < 4; i++)
#pragma unroll
        for (int j = 0; j < 4; j++) acc[i][j] = (f32x4){0.f, 0.f, 0.f, 0.f};

    const int cbase = (wid * 4) << 6;  // chunk base for this wave (64 chunks/call)

    for (int kt = 0; kt < 8; ++kt) {
        const int k0 = kt * 64;
        __syncthreads();  // previous tile's reads complete
#pragma unroll
        for (int j = 0; j < 4; ++j) {
            int c = cbase + (j << 6) + lane;   // 16B chunk index 0..1023
            int m = c >> 3, kc = c & 7;
            int kcs = kc ^ (m & 7);            // pre-swizzled source chunk
            gld_lds16(Wm + (size_t)(o0 + m) * CC + k0 + kcs * 8,
                      &Al[(cbase + (j << 6)) << 3]);
            gld_lds16(Sm + (size_t)(t0 + m) * CC + k0 + kcs * 8,
                      &Bl[(cbase + (j << 6)) << 3]);
        }
        __syncthreads();  // drains vmcnt(0): staged data visible
#pragma unroll
        for (int kk = 0; kk < 2; ++kk) {
            const int kb = kk * 32 + (lane >> 4) * 8;
            s16x8 af[4], bfr[4];
#pragma unroll
            for (int i = 0; i < 4; i++) {
                int m = wm + i * 16 + (lane & 15);
                af[i] = *(const s16x8*)&Al[(m * 64 + kb) ^ ((m & 7) << 3)];
                int n = wn + i * 16 + (lane & 15);
                bfr[i] = *(const s16x8*)&Bl[(n * 64 + kb) ^ ((n & 7) << 3)];
            }
#pragma unroll
            for (int mi = 0; mi < 4; mi++)
#pragma unroll
                for (int ni = 0; ni < 4; ni++) {
                    if (OMODE == 1)   // rows = t (bfr tile), cols = o (af tile)
                        acc[mi][ni] = __builtin_amdgcn_mfma_f32_16x16x32_bf16(
                            bfr[mi], af[ni], acc[mi][ni], 0, 0, 0);
                    else
                        acc[mi][ni] = __builtin_amdgcn_mfma_f32_16x16x32_bf16(
                            af[mi], bfr[ni], acc[mi][ni], 0, 0, 0);
                }
        }
    }

    const int col = lane & 15;
    const int rg = (lane >> 4) << 2;
    if (OMODE == 1) {
#pragma unroll
        for (int ti = 0; ti < 4; ti++) {
            int t = t0 + wn + ti * 16 + rg;
#pragma unroll
            for (int oi = 0; oi < 4; oi++) {
                int o = o0 + wm + oi * 16 + col;
                float bv = bias[o];
                f32x4 a = acc[ti][oi];
#pragma unroll
                for (int r = 0; r < 4; r++)
                    Db[(size_t)(t + r) * CC + o] = f2bf(a[r] + bv);
            }
        }
    } else {
#pragma unroll
        for (int mi = 0; mi < 4; mi++) {
            int o = o0 + wm + mi * 16 + rg;
#pragma unroll
            for (int ni = 0; ni < 4; ni++) {
                int t = t0 + wn + ni * 16 + col;
                f32x4 a = acc[mi][ni];
#pragma unroll
                for (int r = 0; r < 4; r++) {
                    if (OMODE == 0)
                        Df[(size_t)(o + r) * TT + t] = a[r] + bias[o + r];
                    else
                        Db[(size_t)(o + r) * TT + t] = f2bf(a[r] + bias[o + r]);
                }
            }
        }
    }
}

// QKV: Q,K -> bf16 [b][t][C]; V -> bf16 [b][c][t]
__global__ __launch_bounds__(256, 2) void gemm_qkv_k(
    const short* __restrict__ Wb, const short* __restrict__ xT,
    const short* __restrict__ condT, const float* __restrict__ bq,
    const float* __restrict__ bk, const float* __restrict__ bv,
    short* __restrict__ qkvT) {
    int z = blockIdx.z, which = z >> 2, b = z & 3;
    const short* Wm = Wb + (size_t)which * CC * CC;
    const short* Sm = (which == 0 ? xT : condT) + (size_t)b * TT * CC;
    short* Db = qkvT + ((size_t)which * NB + b) * TT * CC;
    if (which == 2)
        gemm128<2>(Wm, Sm, bv, nullptr, Db);
    else
        gemm128<1>(Wm, Sm, which == 0 ? bq : bk, nullptr, Db);
}

__global__ __launch_bounds__(256, 2) void gemm_o_k(const short* __restrict__ Wb,
                                                   const short* __restrict__ outT,
                                                   const float* __restrict__ bo,
                                                   float* __restrict__ out) {
    int b = blockIdx.z;
    gemm128<0>(Wb + 3 * (size_t)CC * CC, outT + (size_t)b * TT * CC, bo,
               out + (size_t)b * CC * TT, nullptr);
}

// ---------------- windowed attention v6: MFMA-based ----------------
// Q,K bf16 [b][t][C]; V bf16 [b][c][t]; out bf16 [b][t][C].
// Block = 1 wave = 32 t-rows of one (b,h). Per 16-t block m:
//  S^T(32s x 16t) = mfma(K_rows, Q_rows) x4; softmax in C/D layout
//  (cols = t are lane-resident; reduce over s = regs + shfl_xor 16/32);
//  P bounced via LDS [t][s] (b64 writes -> b128 row-frag reads);
//  out^T(64d x 16t) = mfma(VT_rows, P_rows) x4.
__global__ __launch_bounds__(64, 4) void attn6_k(const short* __restrict__ qkvT,
                                                 short* __restrict__ outT) {
    __shared__ unsigned P_lds[2][16][18];  // [dbuf][t][s-dwords], 72B row stride
    const int lane = threadIdx.x;
    const int g = lane >> 4, tp = lane & 15;
    const int T0 = blockIdx.x * 32;
    const int h = blockIdx.y, b = blockIdx.z;
    const size_t BTC = (size_t)NB * TT * CC;
    const short* qg = qkvT + (size_t)b * TT * CC + h * HD;
    const short* kg = qg + BTC;
    const short* vg = qkvT + 2 * BTC + (size_t)b * TT * CC + (size_t)(h * HD) * TT;
    const f32x4 z4 = {0.f, 0.f, 0.f, 0.f};

    // K fragment for key-block base T0-8 (shared j=0 of m=0)
    s16x8 ka0, ka1;
    {
        int s = T0 - 8 + tp;
        s = s < 0 ? 0 : s;
        const short* p = &kg[(size_t)s * CC + g * 8];
        ka0 = *(const s16x8*)p;
        ka1 = *(const s16x8*)(p + 32);
    }

#pragma unroll
    for (int m = 0; m < 2; ++m) {
        const int sb0 = T0 + 16 * m - 8;   // key band base for this t-block
        // j=1 key block (rows sb0+16..sb0+31)
        s16x8 kb0, kb1;
        {
            int s = sb0 + 16 + tp;
            s = s > TT - 1 ? TT - 1 : s;
            const short* p = &kg[(size_t)s * CC + g * 8];
            kb0 = *(const s16x8*)p;
            kb1 = *(const s16x8*)(p + 32);
        }
        // Q fragments (t-rows T0+16m..+15)
        s16x8 q0, q1;
        {
            const short* p = &qg[(size_t)(T0 + 16 * m + tp) * CC + g * 8];
            q0 = *(const s16x8*)p;
            q1 = *(const s16x8*)(p + 32);
        }
        // V^T fragments: row d = dblk*16+tp, cols [cb, cb+8)
        int cb = sb0 + g * 8;
        cb = cb < 0 ? 0 : (cb > TT - 8 ? TT - 8 : cb);
        const short* vrow = &vg[(size_t)tp * TT + cb];
        s16x8 vf0 = *(const s16x8*)(vrow);
        s16x8 vf1 = *(const s16x8*)(vrow + (size_t)16 * TT);
        s16x8 vf2 = *(const s16x8*)(vrow + (size_t)32 * TT);
        s16x8 vf3 = *(const s16x8*)(vrow + (size_t)48 * TT);

        // S^T = K . Q^T : D[s][t], lane holds s = 16j+4g+r, t = tp
        f32x4 s0 = __builtin_amdgcn_mfma_f32_16x16x32_bf16(ka0, q0, z4, 0, 0, 0);
        s0 = __builtin_amdgcn_mfma_f32_16x16x32_bf16(ka1, q1, s0, 0, 0, 0);
        f32x4 s1 = __builtin_amdgcn_mfma_f32_16x16x32_bf16(kb0, q0, z4, 0, 0, 0);
        s1 = __builtin_amdgcn_mfma_f32_16x16x32_bf16(kb1, q1, s1, 0, 0, 0);

        // softmax over the 16-wide window of column t=tp (of 32 s-slots)
        float lg[8];
        float mymax = -3.0e38f;
#pragma unroll
        for (int jr = 0; jr < 8; ++jr) {
            const int j = jr >> 2, r = jr & 3;
            float v = (j ? s1[r] : s0[r]) * 0.125f;
            const int sl = 16 * j + 4 * g + r;
            const int sg = sb0 + sl;
            v = ((unsigned)sg < (unsigned)TT) ? v : 0.f;  // zero-pad logit
            lg[jr] = v;
            const bool inw = (unsigned)(sl - tp) < 16u;   // s in [t-8, t+7]
            mymax = inw ? fmaxf(mymax, v) : mymax;
        }
        mymax = fmaxf(mymax, __shfl_xor(mymax, 16));
        mymax = fmaxf(mymax, __shfl_xor(mymax, 32));
        float e[8], Z = 0.f;
#pragma unroll
        for (int jr = 0; jr < 8; ++jr) {
            const int j = jr >> 2, r = jr & 3;
            const int sl = 16 * j + 4 * g + r;
            const bool inw = (unsigned)(sl - tp) < 16u;
            const float ee = inw ? __expf(lg[jr] - mymax) : 0.f;
            e[jr] = ee;
            Z += ee;
        }
        Z += __shfl_xor(Z, 16);
        Z += __shfl_xor(Z, 32);
        const float inv = 1.f / Z;
#pragma unroll
        for (int jr = 0; jr < 8; ++jr) {
            const int sg = sb0 + 16 * (jr >> 2) + 4 * g + (jr & 3);
            e[jr] = ((unsigned)sg < (unsigned)TT) ? e[jr] * inv : 0.f;  // numerator mask
        }

        // bounce P to LDS in [t][s] layout (row-frag form for PV)
        unsigned* prow = &P_lds[m & 1][tp][0];
        *(u32x2*)&prow[2 * g] = (u32x2){pkbf(e[0], e[1]), pkbf(e[2], e[3])};
        *(u32x2*)&prow[8 + 2 * g] = (u32x2){pkbf(e[4], e[5]), pkbf(e[6], e[7])};
        __syncthreads();
        const s16x8 pf = *(const s16x8*)&P_lds[m & 1][tp][4 * g];

        // out^T = V^T . P^T : D[d][t], lane holds d = 4g+r, t = tp
        f32x4 o0 = __builtin_amdgcn_mfma_f32_16x16x32_bf16(vf0, pf, z4, 0, 0, 0);
        f32x4 o1 = __builtin_amdgcn_mfma_f32_16x16x32_bf16(vf1, pf, z4, 0, 0, 0);
        f32x4 o2 = __builtin_amdgcn_mfma_f32_16x16x32_bf16(vf2, pf, z4, 0, 0, 0);
        f32x4 o3 = __builtin_amdgcn_mfma_f32_16x16x32_bf16(vf3, pf, z4, 0, 0, 0);

        short* orow = &outT[((size_t)b * TT + T0 + 16 * m + tp) * CC + h * HD + 4 * g];
        *(u32x2*)&orow[0] = (u32x2){pkbf(o0[0], o0[1]), pkbf(o0[2], o0[3])};
        *(u32x2*)&orow[16] = (u32x2){pkbf(o1[0], o1[1]), pkbf(o1[2], o1[3])};
        *(u32x2*)&orow[32] = (u32x2){pkbf(o2[0], o2[1]), pkbf(o2[2], o2[3])};
        *(u32x2*)&orow[48] = (u32x2){pkbf(o3[0], o3[1]), pkbf(o3[2], o3[3])};

        ka0 = kb0;  // j=1 block of m is j=0 block of m+1
        ka1 = kb1;
    }
}

extern "C" void kernel_launch(void* const* d_in, const int* in_sizes, int n_in,
                              void* d_out, int out_size, void* d_ws, size_t ws_size,
                              hipStream_t stream) {
    const float* x    = (const float*)d_in[0];
    const float* cond = (const float*)d_in[1];
    const float* Wq   = (const float*)d_in[2];
    const float* bq   = (const float*)d_in[3];
    const float* Wk   = (const float*)d_in[4];
    const float* bk   = (const float*)d_in[5];
    const float* Wv   = (const float*)d_in[6];
    const float* bv   = (const float*)d_in[7];
    const float* Wo   = (const float*)d_in[8];
    const float* bo   = (const float*)d_in[9];

    char* ws = (char*)d_ws;
    // layout: Wb(2MB) | xT(16MB) | condT(16MB) | qkv bf16 (48MB: Q,K [b][t][C]; V [b][c][t])
    short* Wb    = (short*)ws;
    short* xT    = (short*)(ws + (2u << 20));
    short* condT = (short*)(ws + (18u << 20));
    short* qkvT  = (short*)(ws + (34u << 20));
    short* outT  = xT;  // xT dead after Q GEMM; reuse for attention output^T

    cvt_w_k<<<4096, 256, 0, stream>>>(Wq, Wk, Wv, Wo, Wb);
    trans_k<<<dim3(TT / 64, CC / 64, 8), 256, 0, stream>>>(x, cond, xT, condT);
    gemm_qkv_k<<<dim3(TT / 128, CC / 128, 12), 256, 0, stream>>>(Wb, xT, condT, bq, bk, bv, qkvT);
    attn6_k<<<dim3(TT / 32, NH, NB), 64, 0, stream>>>(qkvT, outT);
    gemm_o_k<<<dim3(TT / 128, CC / 128, 4), 256, 0, stream>>>(Wb, outT, bo, (float*)d_out);
}